// Round 1
// baseline (12948.672 us; speedup 1.0000x reference)
//
#include <hip/hip_runtime.h>
#include <stdint.h>

// Problem constants
#define H2      1024          // 2*H
#define NBATCH  32
#define TSTEPS  2000
#define TC_C    0.01f

// Topology: 8 groups (blockIdx%8 -> same XCD heuristically), 16 WGs/group,
// 4 batches/group, 64 rows/WG, 512 threads (8 waves) per WG.
#define NGROUPS   8
#define WG_PER_G  16
#define BPG       4
#define ROWS_WG   64
#define NTHR      512
#define NBLOCKS   (NGROUPS * WG_PER_G)   // 128 <= 256 CUs -> co-resident

// Output layout (fp32 elements): hn_last | rnn_out | x_last | x_out
#define OFF_RNN   32768
#define OFF_XL    (32768 + 65536000)            // 65,568,768
#define OFF_XO    (32768 + 65536000 + 32768)    // 65,601,536

typedef __attribute__((ext_vector_type(8))) short bf16x8;
typedef __attribute__((ext_vector_type(4))) float f32x4;

__device__ __forceinline__ float clip01(float w) {
  return fminf(fmaxf(w, 1e-15f), 1.0f);
}
// round-to-nearest-even fp32 -> bf16 (inputs finite)
__device__ __forceinline__ short f2bf(float x) {
  uint32_t u = __float_as_uint(x);
  uint32_t r = (u + 0x7fffu + ((u >> 16) & 1u)) >> 16;
  return (short)r;
}

// ---------------------------------------------------------------------------
// Init kernel: x_out/x_last broadcast, h(0) into exchange buf0, zero counters.
// 256 blocks x 256 threads.
// ---------------------------------------------------------------------------
__global__ void stralm_init_kernel(const float* __restrict__ hn,
                                   const float* __restrict__ x,
                                   float* __restrict__ out,
                                   float* __restrict__ ws) {
  const int tid = blockIdx.x * 256 + threadIdx.x;   // 0..65535
  // x_out: [B][T][2H] = broadcast of x[0][b][:]
  const int b  = tid >> 11;            // 2048 threads per batch
  const int r  = tid & 2047;
  const int jq = (r & 255) * 4;        // 256 j-quads cover 1024
  const int t0 = (r >> 8) * 250;       // 8 t-slices of 250
  const float4 xv = *(const float4*)(x + b * H2 + jq);
  float* xo = out + OFF_XO;
  for (int i = 0; i < 250; ++i) {
    const int t = t0 + i;
    *(float4*)(xo + (size_t)(b * TSTEPS + t) * H2 + jq) = xv;
  }
  if (tid < 8192) {  // 8192*4 = 32768 elements
    *(float4*)(ws + tid * 4) = *(const float4*)(hn + tid * 4);          // buf0 = h(0)
    *(float4*)(out + OFF_XL + tid * 4) = *(const float4*)(x + tid * 4); // x_last
  }
  if (tid < 256) ((int*)(ws + 65536))[tid] = 0;      // barrier counters
}

// ---------------------------------------------------------------------------
// Persistent RNN kernel. grid = 128, block = 512.
// ws layout (floats): buf[2][32][1024] at 0..65536, counters (ints) at 65536.
// ---------------------------------------------------------------------------
__global__ __launch_bounds__(NTHR, 2) void stralm_rnn_kernel(
    const float* __restrict__ inp,      // [B][T][4]
    const float* __restrict__ inhib,    // [B][T][2H]
    const float* __restrict__ ss_w,     // str2str_w   [512][512]
    const float* __restrict__ a2a_w,    // alm2alm_w
    const float* __restrict__ a2s_w,    // alm2str_w
    const float* __restrict__ s2a_w,    // str2alm_w
    const float* __restrict__ iw,       // inp_weight  [4][1024]
    const float* __restrict__ ss_fix,   // str2str_fixed
    const float* __restrict__ ss_mask,  // str2str_mask
    const float* __restrict__ a2s_mask, // alm2str_mask
    const float* __restrict__ sign_v,   // alm2alm_sign [512]
    const float* __restrict__ d1mask,   // str_d1_mask  [1024]
    float* __restrict__ out,
    float* __restrict__ ws) {
  // smem partitions: init: wstage ushort[16][1032] (8256 fl)
  //                  loop: h_lds float[4][1028] (4112 fl) + red float[8][320] (2560 fl)
  __shared__ __align__(16) float smem[8448];

  const int tid = threadIdx.x;
  const int g   = blockIdx.x & 7;    // group
  const int wg  = blockIdx.x >> 3;   // 0..15 within group
  const int r0  = wg * ROWS_WG;      // row slice base
  const int l   = tid & 63;          // lane
  const int wv  = tid >> 6;          // wave 0..7 (k-slice of 128)

  float* buf = ws;                                   // [2][32][1024]
  int*   cnt = (int*)(ws + 65536) + g * 32;          // per-group counter, own line

  // ---- Build W_rec rows [r0, r0+64) as bf16 A-fragments in registers ------
  // A-frag layout (16x16x32): lane supplies A[m = l&15, k = (l>>4)*8 + j].
  bf16x8 afr[4][4];   // [mtile][ktile-within-wave-slice]
  {
    unsigned short* wstage = (unsigned short*)smem;  // [16][1032] padded
#pragma unroll
    for (int mt = 0; mt < 4; ++mt) {
      __syncthreads();
      for (int i = 0; i < 32; ++i) {
        const int idx = i * NTHR + tid;        // 16*1024 entries
        const int jt  = idx >> 10;             // row in tile
        const int k   = idx & 1023;
        const int jg  = r0 + mt * 16 + jt;     // global row
        const int jq  = jg & 511;
        float w;
        if (jg < 512) {
          if (k < 512)
            w = -(ss_mask[jq * 512 + k] * clip01(ss_w[jq * 512 + k]) +
                  ss_fix[jq * 512 + k]);
          else {
            const int kk = k - 512;
            w = a2s_mask[jq * 512 + kk] * clip01(a2s_w[jq * 512 + kk]);
          }
        } else {
          if (k < 512)
            w = clip01(s2a_w[jq * 512 + k]);
          else {
            const int kk = k - 512;
            w = clip01(a2a_w[jq * 512 + kk]) * sign_v[kk];
          }
        }
        wstage[jt * 1032 + k] = (unsigned short)f2bf(w);
      }
      __syncthreads();
#pragma unroll
      for (int kt = 0; kt < 4; ++kt)
        afr[mt][kt] = *(const bf16x8*)&wstage[(l & 15) * 1032 + wv * 128 +
                                              kt * 32 + (l >> 4) * 8];
    }
  }
  __syncthreads();

  float* h_lds = smem;               // [4][1028] fp32 h(t), padded vs bank conflicts
  float* red   = smem + 4 * 1028;    // [8][64*5] wave partials, padded

  // ---- epilogue-thread (tid<256) static state ----
  const bool sumth = (tid < 256);
  const int  sb   = tid >> 6;        // batch in group
  const int  sm   = tid & 63;        // row in slice
  const int  bg   = g * BPG + sb;    // global batch
  const int  grow = r0 + sm;         // global row
  float iw0 = 0.f, iw1 = 0.f, iw2 = 0.f, iw3 = 0.f, dmask = 0.f;
  float inh_cur = 0.f;
  float4 ip_cur = {0.f, 0.f, 0.f, 0.f};
  if (sumth) {
    iw0 = iw[0 * H2 + grow]; iw1 = iw[1 * H2 + grow];
    iw2 = iw[2 * H2 + grow]; iw3 = iw[3 * H2 + grow];
    dmask   = d1mask[grow];
    inh_cur = inhib[(size_t)bg * TSTEPS * H2 + grow];
    ip_cur  = *(const float4*)(inp + bg * (TSTEPS * 4));
  }
  const int stb = tid >> 7;          // staging: batch 0..3
  const int sto = (tid & 127) * 8;   // staging: 8 floats each

  // ---- time loop -----------------------------------------------------------
  for (int t = 0; t < TSTEPS; ++t) {
    const int p = t & 1;
    {  // stage h(t): global buf[p] (group's 4 batches) -> LDS
      const float* src = buf + p * 32768 + (g * BPG + stb) * H2 + sto;
      const float4 v0 = *(const float4*)src;
      const float4 v1 = *(const float4*)(src + 4);
      *(float4*)&h_lds[stb * 1028 + sto]     = v0;
      *(float4*)&h_lds[stb * 1028 + sto + 4] = v1;
    }
    __syncthreads();

    // B-frags: lane supplies B[k=(l>>4)*8+j, n=l&15]; batches live in n=0..3,
    // n>=4 lanes read batch l&3 (their D columns are unused).
    const int bb = l & 3;
    const int kb = (l >> 4) * 8;
    bf16x8 bfr[4];
#pragma unroll
    for (int kt = 0; kt < 4; ++kt) {
      const float* hp = &h_lds[bb * 1028 + wv * 128 + kt * 32 + kb];
      const float4 h0 = *(const float4*)hp;
      const float4 h1 = *(const float4*)(hp + 4);
      bf16x8 f;
      f[0] = f2bf(h0.x); f[1] = f2bf(h0.y); f[2] = f2bf(h0.z); f[3] = f2bf(h0.w);
      f[4] = f2bf(h1.x); f[5] = f2bf(h1.y); f[6] = f2bf(h1.z); f[7] = f2bf(h1.w);
      bfr[kt] = f;
    }

    f32x4 acc[4];
#pragma unroll
    for (int mt = 0; mt < 4; ++mt) acc[mt] = (f32x4){0.f, 0.f, 0.f, 0.f};
#pragma unroll
    for (int mt = 0; mt < 4; ++mt)
#pragma unroll
      for (int kt = 0; kt < 4; ++kt)
        acc[mt] = __builtin_amdgcn_mfma_f32_16x16x32_bf16(afr[mt][kt], bfr[kt],
                                                          acc[mt], 0, 0, 0);
    // partials -> LDS (C/D: col=lane&15, row=(lane>>4)*4+reg)
    if ((l & 15) < 4) {
      const int n = l & 15, h4 = l >> 4;
#pragma unroll
      for (int mt = 0; mt < 4; ++mt)
#pragma unroll
        for (int q = 0; q < 4; ++q)
          red[wv * 320 + (mt * 16 + h4 * 4 + q) * 5 + n] = acc[mt][q];
    }
    __syncthreads();

    if (sumth) {
      float s = 0.f;
#pragma unroll
      for (int w8 = 0; w8 < 8; ++w8) s += red[w8 * 320 + sm * 5 + sb];
      const float d    = dmask * (iw0 * ip_cur.x + iw1 * ip_cur.y +
                                  iw2 * ip_cur.z + iw3 * ip_cur.w) + inh_cur;
      const float hold = h_lds[sb * 1028 + grow];
      const float hnew = fmaxf(0.f, (1.f - TC_C) * hold + TC_C * (s + d));
      buf[(p ^ 1) * 32768 + bg * H2 + grow] = hnew;                 // exchange
      __builtin_nontemporal_store(
          hnew, out + OFF_RNN + (size_t)bg * (TSTEPS * H2) + t * H2 + grow);
      if (t == TSTEPS - 1) out[bg * H2 + grow] = hnew;              // hn_last
      // prefetch drive inputs for t+1 (overlaps barrier)
      const int tn = (t < TSTEPS - 1) ? t + 1 : TSTEPS - 1;
      inh_cur = inhib[((size_t)bg * TSTEPS + tn) * H2 + grow];
      ip_cur  = *(const float4*)(inp + bg * (TSTEPS * 4) + tn * 4);
    }
    __syncthreads();

    // group barrier: monotonic counter, agent scope (cross-XCD safe)
    if (tid == 0) {
      __threadfence();  // release: drain + make h stores device-visible
      __hip_atomic_fetch_add(cnt, 1, __ATOMIC_RELAXED, __HIP_MEMORY_SCOPE_AGENT);
      const int target = WG_PER_G * (t + 1);
      while (__hip_atomic_load(cnt, __ATOMIC_RELAXED, __HIP_MEMORY_SCOPE_AGENT) <
             target)
        __builtin_amdgcn_s_sleep(1);
      __threadfence();  // acquire: invalidate L1/L2 so fresh h is read
    }
    __syncthreads();
  }
}

// ---------------------------------------------------------------------------
extern "C" void kernel_launch(void* const* d_in, const int* in_sizes, int n_in,
                              void* d_out, int out_size, void* d_ws,
                              size_t ws_size, hipStream_t stream) {
  const float* inp      = (const float*)d_in[0];
  const float* hn       = (const float*)d_in[1];
  const float* x        = (const float*)d_in[2];
  const float* inhib    = (const float*)d_in[3];
  const float* ss_w     = (const float*)d_in[4];
  const float* a2a_w    = (const float*)d_in[5];
  const float* a2s_w    = (const float*)d_in[6];
  const float* s2a_w    = (const float*)d_in[7];
  const float* iw       = (const float*)d_in[8];
  const float* ss_fix   = (const float*)d_in[9];
  const float* ss_mask  = (const float*)d_in[10];
  const float* a2s_mask = (const float*)d_in[11];
  const float* sign_v   = (const float*)d_in[12];
  const float* d1mask   = (const float*)d_in[13];
  float* out = (float*)d_out;
  float* ws  = (float*)d_ws;

  hipLaunchKernelGGL(stralm_init_kernel, dim3(256), dim3(256), 0, stream,
                     hn, x, out, ws);
  hipLaunchKernelGGL(stralm_rnn_kernel, dim3(NBLOCKS), dim3(NTHR), 0, stream,
                     inp, inhib, ss_w, a2a_w, a2s_w, s2a_w, iw, ss_fix,
                     ss_mask, a2s_mask, sign_v, d1mask, out, ws);
}

// Round 2
// 4858.443 us; speedup vs baseline: 2.6652x; 2.6652x over previous
//
#include <hip/hip_runtime.h>
#include <stdint.h>

// Problem constants
#define H2      1024          // 2*H
#define TSTEPS  2000
#define TC_C    0.01f

// Topology: 8 groups x 8 WGs; 4 batches/group; 128 rows/WG; 512 thr (8 waves).
#define NGROUPS   8
#define WG_PER_G  8
#define BPG       4
#define ROWS_WG   128
#define NTHR      512
#define NBLOCKS   (NGROUPS * WG_PER_G)   // 64

// Output layout (fp32 elements): hn_last | rnn_out | x_last | x_out
#define OFF_RNN   32768
#define OFF_XL    (32768 + 65536000)
#define OFF_XO    (OFF_XL + 32768)

// ws layout: bufu uint[2][32][512] (bf16-pair h exchange, 128 KB) at 0;
//            flags int[8][32] at int-offset 32768 (one 128B line per group)

typedef __attribute__((ext_vector_type(8))) short bf16x8;
typedef __attribute__((ext_vector_type(4))) float f32x4;

__device__ __forceinline__ float clip01(float w) {
  return fminf(fmaxf(w, 1e-15f), 1.0f);
}
// round-to-nearest-even fp32 -> bf16 (low 16 bits of result)
__device__ __forceinline__ uint32_t f2bf(float x) {
  uint32_t u = __float_as_uint(x);
  return ((u + 0x7fffu + ((u >> 16) & 1u)) >> 16) & 0xffffu;
}

// ---------------------------------------------------------------------------
// Init: x_out/x_last broadcast, bf16 h(0) into exchange buf0, zero flags.
// 256 blocks x 256 threads.
// ---------------------------------------------------------------------------
__global__ void stralm_init_kernel(const float* __restrict__ hn,
                                   const float* __restrict__ x,
                                   float* __restrict__ out,
                                   float* __restrict__ ws) {
  const int tid = blockIdx.x * 256 + threadIdx.x;   // 0..65535
  const int b  = tid >> 11;
  const int r  = tid & 2047;
  const int jq = (r & 255) * 4;
  const int t0 = (r >> 8) * 250;
  const float4 xv = *(const float4*)(x + b * H2 + jq);
  float* xo = out + OFF_XO;
  for (int i = 0; i < 250; ++i) {
    const int t = t0 + i;
    *(float4*)(xo + (size_t)(b * TSTEPS + t) * H2 + jq) = xv;
  }
  if (tid < 8192) {  // 8192*4 = 32768 h values -> bf16 pairs
    const float4 hv = *(const float4*)(hn + tid * 4);
    uint32_t* bufu = (uint32_t*)ws;
    uint2 pk;
    pk.x = f2bf(hv.x) | (f2bf(hv.y) << 16);
    pk.y = f2bf(hv.z) | (f2bf(hv.w) << 16);
    *(uint2*)(bufu + tid * 2) = pk;
    *(float4*)(out + OFF_XL + tid * 4) = *(const float4*)(x + tid * 4);
  }
  if (tid < 256) ((int*)ws)[32768 + tid] = 0;   // flags
}

// ---------------------------------------------------------------------------
// Persistent RNN kernel. grid = 64, block = 512.
// ---------------------------------------------------------------------------
__global__ __launch_bounds__(NTHR, 2) void stralm_rnn_kernel(
    const float* __restrict__ inp,      // [B][T][4]
    const float* __restrict__ hn,       // [1][B][2H] fp32 h(0)
    const float* __restrict__ inhib,    // [B][T][2H]
    const float* __restrict__ ss_w, const float* __restrict__ a2a_w,
    const float* __restrict__ a2s_w, const float* __restrict__ s2a_w,
    const float* __restrict__ iw,       // [4][2H]
    const float* __restrict__ ss_fix, const float* __restrict__ ss_mask,
    const float* __restrict__ a2s_mask, const float* __restrict__ sign_v,
    const float* __restrict__ d1mask,
    float* __restrict__ out, float* __restrict__ ws) {
  // smem: init-phase wstage ushort[16][1032] (33024B);
  //       loop-phase h_lds uint[4][516] (8256B) + red float[8][4][134] @ +2080
  __shared__ __align__(16) float smem[8448];

  const int tid = threadIdx.x;
  const int g   = blockIdx.x & 7;    // group
  const int wg  = blockIdx.x >> 3;   // 0..7
  const int r0  = wg * ROWS_WG;
  const int l   = tid & 63;
  const int wv  = tid >> 6;          // wave 0..7 = K-slice of 128

  uint32_t* bufu  = (uint32_t*)ws;            // [2][32][512]
  int*      flags = (int*)ws + 32768 + g * 32;

  // ---- Build W_rec rows [r0, r0+128) as bf16 MFMA A-frags in registers ----
  bf16x8 afr[8][4];
  {
    unsigned short* wstage = (unsigned short*)smem;  // [16][1032]
#pragma unroll
    for (int mt = 0; mt < 8; ++mt) {
      __syncthreads();
      for (int i = 0; i < 32; ++i) {
        const int idx = i * NTHR + tid;        // 16*1024
        const int jt  = idx >> 10;
        const int k   = idx & 1023;
        const int jg  = r0 + mt * 16 + jt;
        const int jq  = jg & 511;
        float w;
        if (jg < 512) {
          if (k < 512)
            w = -(ss_mask[jq * 512 + k] * clip01(ss_w[jq * 512 + k]) +
                  ss_fix[jq * 512 + k]);
          else {
            const int kk = k - 512;
            w = a2s_mask[jq * 512 + kk] * clip01(a2s_w[jq * 512 + kk]);
          }
        } else {
          if (k < 512)
            w = clip01(s2a_w[jq * 512 + k]);
          else {
            const int kk = k - 512;
            w = clip01(a2a_w[jq * 512 + kk]) * sign_v[kk];
          }
        }
        wstage[jt * 1032 + k] = (unsigned short)f2bf(w);
      }
      __syncthreads();
#pragma unroll
      for (int kt = 0; kt < 4; ++kt)
        afr[mt][kt] = *(const bf16x8*)&wstage[(l & 15) * 1032 + wv * 128 +
                                              kt * 32 + (l >> 4) * 8];
    }
  }
  __syncthreads();

  uint32_t* h_lds = (uint32_t*)smem;   // [4][516] bf16-pairs of h(t)
  float*    red   = smem + 2080;       // [8][4][134] wave partials

  // ---- epilogue-thread (tid<256) static state: 2 rows x 1 batch each ----
  const bool eth  = (tid < 256);
  const int  sb   = tid >> 6;          // batch in group
  const int  ml   = (tid & 63) * 2;    // local row (even)
  const int  bg   = g * BPG + sb;
  const int  grow = r0 + ml;
  float2 iwv[4]; float2 dmv = {0.f, 0.f};
  float2 inh_cur = {0.f, 0.f};
  float4 ip_cur  = {0.f, 0.f, 0.f, 0.f};
  float  hold0 = 0.f, hold1 = 0.f;
  if (eth) {
#pragma unroll
    for (int i = 0; i < 4; ++i) iwv[i] = *(const float2*)(iw + i * H2 + grow);
    dmv     = *(const float2*)(d1mask + grow);
    inh_cur = *(const float2*)(inhib + (size_t)bg * TSTEPS * H2 + grow);
    ip_cur  = *(const float4*)(inp + bg * (TSTEPS * 4));
    const float2 h0 = *(const float2*)(hn + bg * H2 + grow);
    hold0 = h0.x; hold1 = h0.y;
  }

  for (int t = 0; t < TSTEPS; ++t) {
    const int p = t & 1;
    // ---- wait for h(t): all group flags >= t ----
    if (tid < WG_PER_G) {
      const int* fl = flags + tid;
      while (__hip_atomic_load(fl, __ATOMIC_RELAXED,
                               __HIP_MEMORY_SCOPE_AGENT) < t)
        __builtin_amdgcn_s_sleep(1);
    }
    __syncthreads();

    // ---- load group h(t) bf16 from LLC -> LDS ----
    uint32_t hv[4];
    const int ubase = p * 16384 + g * 2048;
#pragma unroll
    for (int j = 0; j < 4; ++j)
      hv[j] = __hip_atomic_load(bufu + ubase + j * NTHR + tid,
                                __ATOMIC_RELAXED, __HIP_MEMORY_SCOPE_AGENT);
#pragma unroll
    for (int j = 0; j < 4; ++j) {
      const int f = j * NTHR + tid;           // 0..2047
      h_lds[(f >> 9) * 516 + (f & 511)] = hv[j];
    }
    __syncthreads();

    // ---- B-frags straight from LDS (already bf16) ----
    const int bb = l & 3;
    const int kb = (l >> 4) * 8;
    const unsigned short* hs = (const unsigned short*)h_lds;
    bf16x8 bfr[4];
#pragma unroll
    for (int kt = 0; kt < 4; ++kt)
      bfr[kt] = *(const bf16x8*)&hs[bb * 1032 + wv * 128 + kt * 32 + kb];

    f32x4 acc[8];
#pragma unroll
    for (int mt = 0; mt < 8; ++mt) acc[mt] = (f32x4){0.f, 0.f, 0.f, 0.f};
#pragma unroll
    for (int mt = 0; mt < 8; ++mt)
#pragma unroll
      for (int kt = 0; kt < 4; ++kt)
        acc[mt] = __builtin_amdgcn_mfma_f32_16x16x32_bf16(afr[mt][kt], bfr[kt],
                                                          acc[mt], 0, 0, 0);
    // partials -> LDS: red[wv][n][row], n=batch, row = mt*16 + (l>>4)*4 + q
    if ((l & 15) < 4) {
      const int n = l & 15, h4 = l >> 4;
#pragma unroll
      for (int mt = 0; mt < 8; ++mt)
#pragma unroll
        for (int q = 0; q < 4; ++q)
          red[wv * 536 + n * 134 + mt * 16 + h4 * 4 + q] = acc[mt][q];
    }
    __syncthreads();

    if (eth) {
      float s0 = 0.f, s1 = 0.f;
#pragma unroll
      for (int w8 = 0; w8 < 8; ++w8) {
        const float2 rv = *(const float2*)&red[w8 * 536 + sb * 134 + ml];
        s0 += rv.x; s1 += rv.y;
      }
      const float din0 = dmv.x * (iwv[0].x * ip_cur.x + iwv[1].x * ip_cur.y +
                                  iwv[2].x * ip_cur.z + iwv[3].x * ip_cur.w) +
                         inh_cur.x;
      const float din1 = dmv.y * (iwv[0].y * ip_cur.x + iwv[1].y * ip_cur.y +
                                  iwv[2].y * ip_cur.z + iwv[3].y * ip_cur.w) +
                         inh_cur.y;
      const float hn0 = fmaxf(0.f, (1.f - TC_C) * hold0 + TC_C * (s0 + din0));
      const float hn1 = fmaxf(0.f, (1.f - TC_C) * hold1 + TC_C * (s1 + din1));
      hold0 = hn0; hold1 = hn1;
      // exchange: packed bf16 pair, write-through to LLC (agent scope)
      const uint32_t pk = f2bf(hn0) | (f2bf(hn1) << 16);
      __hip_atomic_store(bufu + (p ^ 1) * 16384 + bg * 512 + (grow >> 1), pk,
                         __ATOMIC_RELAXED, __HIP_MEMORY_SCOPE_AGENT);
      // rnn_out (nontemporal 8B)
      const uint64_t u64 = (uint64_t)__float_as_uint(hn0) |
                           ((uint64_t)__float_as_uint(hn1) << 32);
      __builtin_nontemporal_store(
          u64, (uint64_t*)(out + OFF_RNN +
                           (size_t)bg * (TSTEPS * H2) + (size_t)t * H2 + grow));
      if (t == TSTEPS - 1) {
        out[bg * H2 + grow]     = hn0;
        out[bg * H2 + grow + 1] = hn1;
      }
    }
    // drain this wave's stores, WG barrier, publish flag
    asm volatile("s_waitcnt vmcnt(0)" ::: "memory");
    __syncthreads();
    if (tid == 0)
      __hip_atomic_store(flags + wg, t + 1, __ATOMIC_RELAXED,
                         __HIP_MEMORY_SCOPE_AGENT);
    // prefetch drive inputs for t+1 (completes during next poll/MFMA)
    if (eth) {
      const int tn = (t < TSTEPS - 1) ? t + 1 : TSTEPS - 1;
      inh_cur = *(const float2*)(inhib + ((size_t)bg * TSTEPS + tn) * H2 + grow);
      ip_cur  = *(const float4*)(inp + bg * (TSTEPS * 4) + tn * 4);
    }
  }
}

// ---------------------------------------------------------------------------
extern "C" void kernel_launch(void* const* d_in, const int* in_sizes, int n_in,
                              void* d_out, int out_size, void* d_ws,
                              size_t ws_size, hipStream_t stream) {
  const float* inp      = (const float*)d_in[0];
  const float* hn       = (const float*)d_in[1];
  const float* x        = (const float*)d_in[2];
  const float* inhib    = (const float*)d_in[3];
  const float* ss_w     = (const float*)d_in[4];
  const float* a2a_w    = (const float*)d_in[5];
  const float* a2s_w    = (const float*)d_in[6];
  const float* s2a_w    = (const float*)d_in[7];
  const float* iw       = (const float*)d_in[8];
  const float* ss_fix   = (const float*)d_in[9];
  const float* ss_mask  = (const float*)d_in[10];
  const float* a2s_mask = (const float*)d_in[11];
  const float* sign_v   = (const float*)d_in[12];
  const float* d1mask   = (const float*)d_in[13];
  float* out = (float*)d_out;
  float* ws  = (float*)d_ws;

  hipLaunchKernelGGL(stralm_init_kernel, dim3(256), dim3(256), 0, stream,
                     hn, x, out, ws);
  hipLaunchKernelGGL(stralm_rnn_kernel, dim3(NBLOCKS), dim3(NTHR), 0, stream,
                     inp, hn, inhib, ss_w, a2a_w, a2s_w, s2a_w, iw, ss_fix,
                     ss_mask, a2s_mask, sign_v, d1mask, out, ws);
}